// Round 14
// baseline (173.415 us; speedup 1.0000x reference)
//
#include <hip/hip_runtime.h>
#include <cstdint>

// Lukasiewicz max-plus matmul: y[n,o] = max(b[o], max(0, max_i(x[n,i]+a[o,i]-1)))
// N=2048, K=512, OUT=512, fp32.
//
// R14: row-split waves, no merge. R13 (k-split) measured: no spill, VALU
// busy-time 14.1us == fully-scalarized op count, but 70% stall at 2 waves/
// SIMD + 32KB merge buffer capping blocks/CU. Fix: each wave owns 1 row x
// 256 cols x FULL K -> partials never cross waves -> no red buffer, no merge
// pass. LDS = 8KB X slab only; grid (2,512) = 1024 blocks = 4 blk/CU =
// 4 waves/SIMD (2x R13 TLP). All waves read the SAME A addresses (no k-split)
// -> cross-wave L1 reuse (nontemporal dropped deliberately). ds reads are
// base + j*16 immediates -> zero addressing VALU in the loop.

#define NROW 2048
#define NK   512
#define NCOL 512
#define RPB  4                    // rows per block (1 per wave)
#define CBL  256                  // cols per block (4 per lane)
typedef float f32x4 __attribute__((ext_vector_type(4)));

__device__ __forceinline__ void async_load16(const float* g, float* l) {
  __builtin_amdgcn_global_load_lds(
      (const __attribute__((address_space(1))) void*)g,
      (__attribute__((address_space(3))) void*)l, 16, 0, 0);
}

// ---- prep: Apc[(cb*128 + k4)*256 + l*4 + c] = A[cb*256 + c*64 + l][4k4..] --
// Per-lane 64B-contiguous: lane l's 4 cols at byte offsets 0/16/32/48.
__global__ __launch_bounds__(256) void luka_prep(const float* __restrict__ A,
                                                 f32x4* __restrict__ Apc) {
  int idx = blockIdx.x * 256 + threadIdx.x;   // 512 cols * 128 k4
  int o  = idx >> 7;                          // source col
  int k4 = idx & 127;
  int cb = o >> 8, oc = o & 255;
  int c  = oc >> 6, l = oc & 63;
  f32x4 v = *(const f32x4*)(A + o * NK + k4 * 4);      // coalesced read
  Apc[((cb * 128 + k4) << 8) + (l << 2) + c] = v;      // 1MB one-shot
}

// ---- main -----------------------------------------------------------------
__global__ __launch_bounds__(256) void luka_main(
    const f32x4* __restrict__ Apc, const float* __restrict__ X,
    const float* __restrict__ Bv, float* __restrict__ Y) {
  __shared__ float xsl[RPB * NK];        // 8KB X slab (4 rows)
  const int tid  = threadIdx.x;
  const int lane = tid & 63;
  const int w    = tid >> 6;             // wave id = row within slab
  const int colblk  = blockIdx.x;        // 0..1
  const int rowBase = blockIdx.y * RPB;

  // Stage X[rowBase..+4)[0..512) -> xsl [4][512]; 512 f32x4 by 256 thr in
  // 2 rounds; per-wave LDS dest linear (wave-uniform base + lane*16) ✓.
  {
    const float* Xg = X + (size_t)rowBase * NK;
#pragma unroll
    for (int rnd = 0; rnd < 2; ++rnd) {
      int base = rnd * 256 + w * 64;     // f32x4 index, wave-uniform
      async_load16(Xg + (size_t)(base + lane) * 4, &xsl[base * 4]);
    }
  }

  // A stream: identical addresses for ALL waves (cross-wave L1 reuse).
  const f32x4* __restrict__ Aw =
      Apc + (((size_t)(colblk * 128)) << 8) + (lane << 2);
  // My row in the slab: all loop reads are base + j*16 immediate.
  const float* __restrict__ xrow = &xsl[w * NK];

  float acc0 = 0.0f, acc1 = 0.0f, acc2 = 0.0f, acc3 = 0.0f;  // ref clamps at 0

  __syncthreads();                       // staged X visible (vmcnt drain)

  // prime 1-deep pipeline
  f32x4 xv = *(const f32x4*)xrow;
  f32x4 a0 = Aw[0], a1 = Aw[1], a2 = Aw[2], a3 = Aw[3];

#pragma unroll 2
  for (int j = 0; j < NK / 4; ++j) {
    f32x4 xn, n0, n1, n2, n3;
    if (j + 1 < NK / 4) {                // prefetch next k4 (static names)
      xn = *(const f32x4*)(xrow + (j + 1) * 4);   // ds_read, imm offset
      const f32x4* p = Aw + ((j + 1) << 8);
      n0 = p[0]; n1 = p[1]; n2 = p[2]; n3 = p[3];
    }
    f32x4 s0 = a0 + xv;                  // v_pk_add_f32 candidates
    f32x4 s1 = a1 + xv;
    f32x4 s2 = a2 + xv;
    f32x4 s3 = a3 + xv;
    acc0 = fmaxf(fmaxf(s0.x, s0.y), acc0);  // v_max3 shapes
    acc0 = fmaxf(fmaxf(s0.z, s0.w), acc0);
    acc1 = fmaxf(fmaxf(s1.x, s1.y), acc1);
    acc1 = fmaxf(fmaxf(s1.z, s1.w), acc1);
    acc2 = fmaxf(fmaxf(s2.x, s2.y), acc2);
    acc2 = fmaxf(fmaxf(s2.z, s2.w), acc2);
    acc3 = fmaxf(fmaxf(s3.x, s3.y), acc3);
    acc3 = fmaxf(fmaxf(s3.z, s3.w), acc3);
    xv = xn; a0 = n0; a1 = n1; a2 = n2; a3 = n3;
  }

  // Epilogue: y = max3(acc-1, b, 0); defer of -1 exact (rounding monotone).
  const int row = rowBase + w;
  const int cbase = colblk * CBL + lane;
  float b0 = Bv[cbase], b1 = Bv[cbase + 64], b2 = Bv[cbase + 128],
        b3 = Bv[cbase + 192];
  Y[(size_t)row * NCOL + cbase]       = fmaxf(fmaxf(acc0 - 1.0f, b0), 0.0f);
  Y[(size_t)row * NCOL + cbase + 64]  = fmaxf(fmaxf(acc1 - 1.0f, b1), 0.0f);
  Y[(size_t)row * NCOL + cbase + 128] = fmaxf(fmaxf(acc2 - 1.0f, b2), 0.0f);
  Y[(size_t)row * NCOL + cbase + 192] = fmaxf(fmaxf(acc3 - 1.0f, b3), 0.0f);
}

// ---- fallback (R1 kernel, used only if d_ws < 1MB) ------------------------
#define TILE 64
#define BK   64
__global__ __launch_bounds__(256) void luka_fb(
    const float* __restrict__ X, const float* __restrict__ A,
    const float* __restrict__ Bv, float* __restrict__ Y) {
  __shared__ float xs[2][TILE * BK];
  __shared__ float as[2][TILE * BK];
  const int tid = threadIdx.x, wave = tid >> 6, tx = tid & 15, ty = tid >> 4;
  const int rowBase = blockIdx.y * TILE, colBase = blockIdx.x * TILE;
  uint32_t xoff[4], aoff[4];
#pragma unroll
  for (int r = 0; r < 4; ++r) {
    int row = ty * 4 + r;
    xoff[r] = (uint32_t)row * 256u + ((uint32_t)((row & 15) ^ (row >> 2)) << 4);
  }
#pragma unroll
  for (int c = 0; c < 4; ++c) {
    int row = tx * 4 + c;
    aoff[c] = (uint32_t)row * 256u + ((uint32_t)((row & 15) ^ (row >> 2)) << 4);
  }
  float acc[4][4];
#pragma unroll
  for (int r = 0; r < 4; ++r)
#pragma unroll
    for (int c = 0; c < 4; ++c) acc[r][c] = 0.0f;
  const int row0 = tid >> 4, sl = tid & 15;
  auto stage = [&](int buf, int kt) {
#pragma unroll
    for (int j = 0; j < 4; ++j) {
      int row = row0 + j * 16;
      int m = (row & 15) ^ (row >> 2);
      int kk = ((sl ^ m) << 2);
      async_load16(X + (size_t)(rowBase + row) * NK + kt * BK + kk,
                   &xs[buf][j * 1024 + wave * 256]);
      async_load16(A + (size_t)(colBase + row) * NK + kt * BK + kk,
                   &as[buf][j * 1024 + wave * 256]);
    }
  };
  stage(0, 0);
  __syncthreads();
  int buf = 0;
#pragma unroll 1
  for (int kt = 0; kt < NK / BK; ++kt) {
    if (kt < NK / BK - 1) stage(buf ^ 1, kt + 1);
    const char* xb = (const char*)&xs[buf][0];
    const char* ab = (const char*)&as[buf][0];
#pragma unroll
    for (int s4 = 0; s4 < BK / 4; ++s4) {
      f32x4 xf[4], af[4];
#pragma unroll
      for (int r = 0; r < 4; ++r)
        xf[r] = *(const f32x4*)(xb + (xoff[r] ^ (uint32_t)(s4 << 4)));
#pragma unroll
      for (int c = 0; c < 4; ++c)
        af[c] = *(const f32x4*)(ab + (aoff[c] ^ (uint32_t)(s4 << 4)));
#pragma unroll
      for (int r = 0; r < 4; ++r)
#pragma unroll
        for (int c = 0; c < 4; ++c) {
          f32x4 s = xf[r] + af[c];
          float t0 = fmaxf(fmaxf(s.x, s.y), acc[r][c]);
          acc[r][c] = fmaxf(fmaxf(s.z, s.w), t0);
        }
    }
    __syncthreads();
    buf ^= 1;
  }
  const f32x4 bv = *(const f32x4*)&Bv[colBase + tx * 4];
  float bvv[4] = {bv.x, bv.y, bv.z, bv.w};
#pragma unroll
  for (int r = 0; r < 4; ++r) {
    f32x4 o;
    o.x = fmaxf(fmaxf(acc[r][0] - 1.0f, bvv[0]), 0.0f);
    o.y = fmaxf(fmaxf(acc[r][1] - 1.0f, bvv[1]), 0.0f);
    o.z = fmaxf(fmaxf(acc[r][2] - 1.0f, bvv[2]), 0.0f);
    o.w = fmaxf(fmaxf(acc[r][3] - 1.0f, bvv[3]), 0.0f);
    *(f32x4*)&Y[(size_t)(rowBase + ty * 4 + r) * NCOL + colBase + tx * 4] = o;
  }
}

extern "C" void kernel_launch(void* const* d_in, const int* in_sizes, int n_in,
                              void* d_out, int out_size, void* d_ws, size_t ws_size,
                              hipStream_t stream) {
  const float* X = (const float*)d_in[0];   // [2048][512]
  const float* A = (const float*)d_in[1];   // [512][512]
  const float* B = (const float*)d_in[2];   // [512]
  float* Y = (float*)d_out;                 // [2048][512]

  if (ws_size >= (size_t)NCOL * NK * sizeof(float)) {
    f32x4* Apc = (f32x4*)d_ws;
    luka_prep<<<dim3(NCOL * NK / 4 / 256), dim3(256), 0, stream>>>(A, Apc);
    dim3 grid(NCOL / CBL, NROW / RPB);      // (2, 512) = 1024 blocks, 4/CU
    luka_main<<<grid, dim3(256), 0, stream>>>(Apc, X, B, Y);
  } else {
    dim3 grid(NCOL / TILE, NROW / TILE);    // fallback: R1 kernel
    luka_fb<<<grid, dim3(256), 0, stream>>>(X, A, B, Y);
  }
}